// Round 10
// baseline (188.820 us; speedup 1.0000x reference)
//
#include <hip/hip_runtime.h>
#include <math.h>

#define SLEN 2000
#define BATCH 8
#define MTOK 16000
#define WIN 99
#define XPAD 264

typedef __attribute__((ext_vector_type(8))) short short8;
typedef __attribute__((ext_vector_type(4))) float floatx4;

// ---------- bf16 helpers (bit-level, RNE) ----------
__device__ __forceinline__ float bf2f(unsigned int h) {
  union { unsigned int u; float f; } w; w.u = h << 16; return w.f;
}
__device__ __forceinline__ unsigned short f2bf(float f) {
  union { float f; unsigned int u; } w; w.f = f;
  return (unsigned short)((w.u + 0x7fffu + ((w.u >> 16) & 1u)) >> 16);
}

// ================= prep: 5 weight cvts + posenc + headprep (unchanged) =================
__device__ __forceinline__ void cvt4(const float* __restrict__ in,
                                     unsigned short* __restrict__ out, int i) {
  float4 v = ((const float4*)in)[i];
  ushort4 o;
  o.x = f2bf(v.x); o.y = f2bf(v.y); o.z = f2bf(v.z); o.w = f2bf(v.w);
  ((ushort4*)out)[i] = o;
}

__global__ __launch_bounds__(256) void k_prep(
    const float* __restrict__ wenc,     unsigned short* __restrict__ wencb,
    const float* __restrict__ wqk,      unsigned short* __restrict__ wqkb,
    const float* __restrict__ wout,     unsigned short* __restrict__ woutb,
    const float* __restrict__ wl1,      unsigned short* __restrict__ wl1b,
    const float* __restrict__ wl2,      unsigned short* __restrict__ wl2b,
    float* __restrict__ pe,
    const float* __restrict__ fc1w, const float* __restrict__ fc1b,
    const float* __restrict__ fc2w, const float* __restrict__ fc2b,
    const float* __restrict__ ln2w, const float* __restrict__ ln2b,
    float* __restrict__ hp) {
  __shared__ float red0[4], red1[4];
  const int bx = blockIdx.x, tid = threadIdx.x;
  if (bx < 64)         { cvt4(wenc, wencb, bx * 256 + tid); }
  else if (bx < 256)   { cvt4(wqk,  wqkb,  (bx - 64) * 256 + tid); }
  else if (bx < 320)   { cvt4(wout, woutb, (bx - 256) * 256 + tid); }
  else if (bx < 384)   { cvt4(wl1,  wl1b,  (bx - 320) * 256 + tid); }
  else if (bx < 448)   { cvt4(wl2,  wl2b,  (bx - 384) * 256 + tid); }
  else if (bx < 948) {                                       // posenc, float4/thread
    int i4 = (bx - 448) * 256 + tid;
    int e0 = i4 * 4;
    int s  = e0 >> 8;
    int d0 = e0 & 255;
    float dv0 = expf((float)(d0 >> 1) * -0.07195578415606394f);
    float dv1 = expf((float)((d0 >> 1) + 1) * -0.07195578415606394f);
    float a0 = (float)s * dv0, a1 = (float)s * dv1;
    ((float4*)pe)[i4] = make_float4(sinf(a0), cosf(a0), sinf(a1), cosf(a1));
  } else {                                                   // headprep (1 block)
    int k = tid;
    float we = 0.f;
#pragma unroll 8
    for (int o = 0; o < 64; ++o) we += fc2w[o] * fc1w[o * 256 + k];
    float c1 = ln2w[k] * we;
    hp[k] = c1;
    float p0 = ln2b[k] * we;
    if (k < 64) p0 += fc2w[k] * fc1b[k];
    float s0 = p0, s1 = c1;
#pragma unroll
    for (int off = 32; off; off >>= 1) {
      s0 += __shfl_xor(s0, off);
      s1 += __shfl_xor(s1, off);
    }
    int wv = k >> 6;
    if ((k & 63) == 0) { red0[wv] = s0; red1[wv] = s1; }
    __syncthreads();
    if (k == 0) {
      hp[256] = red0[0] + red0[1] + red0[2] + red0[3] + fc2b[0];
      hp[257] = red1[0] + red1[1] + red1[2] + red1[3];
    }
  }
}

// ================= fused encoder + qkv — 8 waves/block (2 waves/SIMD) =================
// 250 blocks x 512 thr x 64 tokens. Wave w: stage 1 cols [32w,32w+32),
// stage 2 cols [96w,96w+96). B fragments read DIRECT from global (weights are
// L2-resident: 1.3 MB shared by all blocks) — no staging barriers at all.
// Only LDS: Xt transpose array (C-layout -> A-layout between stages).
__global__ __launch_bounds__(512) void k_pre(
    const float* __restrict__ src,
    const unsigned short* __restrict__ wenc, const float* __restrict__ benc,
    const float* __restrict__ pe,
    const unsigned short* __restrict__ wqk, const float* __restrict__ bqk,
    unsigned short* __restrict__ xb, unsigned short* __restrict__ qkvb) {
  __shared__ __align__(16) unsigned short Xt[64 * XPAD];     // 33792 B
  const int tid = threadIdx.x, lane = tid & 63, w = tid >> 6;   // w in 0..7
  const int m0 = blockIdx.x * 64;
  const int kq = lane >> 4, ml = lane & 15;

  // ---- stage 1: x = src @ Wenc^T, wave cols [32w, 32w+32) ----
  {
    const int cb = w * 32;
    floatx4 acc[4][2] = {};
#pragma unroll
    for (int k8 = 0; k8 < 8; ++k8) {
      const int kt = k8 * 32;
      short8 af[4];
#pragma unroll
      for (int mt = 0; mt < 4; ++mt) {
        const float* ap = src + (size_t)(m0 + mt * 16 + ml) * 256 + kt + kq * 8;
        float4 v0 = *(const float4*)ap;
        float4 v1 = *(const float4*)(ap + 4);
        unsigned short t8[8] = {f2bf(v0.x), f2bf(v0.y), f2bf(v0.z), f2bf(v0.w),
                                f2bf(v1.x), f2bf(v1.y), f2bf(v1.z), f2bf(v1.w)};
        af[mt] = *(const short8*)t8;
      }
#pragma unroll
      for (int nt = 0; nt < 2; ++nt) {
        short8 bf = *(const short8*)(wenc + (size_t)(cb + nt * 16 + ml) * 256 + kt + kq * 8);
#pragma unroll
        for (int mt = 0; mt < 4; ++mt)
          acc[mt][nt] = __builtin_amdgcn_mfma_f32_16x16x32_bf16(af[mt], bf, acc[mt][nt], 0, 0, 0);
      }
    }
#pragma unroll
    for (int mt = 0; mt < 4; ++mt)
#pragma unroll
      for (int nt = 0; nt < 2; ++nt)
#pragma unroll
        for (int r = 0; r < 4; ++r) {
          int lrow = mt * 16 + kq * 4 + r;
          int col  = cb + nt * 16 + ml;
          float v = acc[mt][nt][r] + benc[col]
                  + pe[(size_t)((m0 + lrow) % SLEN) * 256 + col];
          unsigned short hv = f2bf(v);
          Xt[lrow * XPAD + col] = hv;
          xb[(size_t)(m0 + lrow) * 256 + col] = hv;
        }
  }
  __syncthreads();

  // ---- stage 2: qkv = Xt @ Wqk^T, wave cols [96w, 96w+96) ----
  {
    const int cb = w * 96;
    floatx4 acc[4][6] = {};
#pragma unroll
    for (int k8 = 0; k8 < 8; ++k8) {
      const int kt = k8 * 32;
      short8 af[4];
#pragma unroll
      for (int mt = 0; mt < 4; ++mt)
        af[mt] = *(const short8*)&Xt[(mt * 16 + ml) * XPAD + kt + kq * 8];
#pragma unroll
      for (int nt = 0; nt < 6; ++nt) {
        short8 bf = *(const short8*)(wqk + (size_t)(cb + nt * 16 + ml) * 256 + kt + kq * 8);
#pragma unroll
        for (int mt = 0; mt < 4; ++mt)
          acc[mt][nt] = __builtin_amdgcn_mfma_f32_16x16x32_bf16(af[mt], bf, acc[mt][nt], 0, 0, 0);
      }
    }
#pragma unroll
    for (int mt = 0; mt < 4; ++mt)
#pragma unroll
      for (int nt = 0; nt < 6; ++nt)
#pragma unroll
        for (int r = 0; r < 4; ++r) {
          int row = m0 + mt * 16 + kq * 4 + r;
          int cg  = cb + nt * 16 + ml;
          qkvb[(size_t)row * 768 + cg] = f2bf(acc[mt][nt][r] + bqk[cg]);
        }
  }
}

// ================= MFMA banded attention (unchanged — verified) =================
#define KPAD 136
#define VPAD 184
#define PPAD 132
#define UNION 176

__global__ __launch_bounds__(256) void k_attn_mfma(const unsigned short* __restrict__ qkv,
                                                   unsigned short* __restrict__ ctx) {
  __shared__ __align__(16) unsigned short KV[UNION * KPAD];
  __shared__ __align__(16) unsigned short Ps[4][16 * PPAD];
  const int tid  = threadIdx.x;
  const int lane = tid & 63;
  const int w    = tid >> 6;
  const int i0   = blockIdx.x * 64;
  const int b    = blockIdx.y;
  const int h    = blockIdx.z;
  const int jmin_u = i0 - WIN;
  const float scale = 0.08838834764831845f;

  const int qrow = i0 + w * 16 + (lane & 15);
  const unsigned short* qptr =
      qkv + (size_t)(b * SLEN + min(qrow, SLEN - 1)) * 768 + h * 128 + (lane >> 4) * 8;
  short8 qf[4];
#pragma unroll
  for (int kc = 0; kc < 4; ++kc) qf[kc] = *(const short8*)(qptr + kc * 32);

  for (int it = 0; it < 11; ++it) {
    int idx = it * 256 + tid;
    int row = idx >> 4;
    int c8  = idx & 15;
    int j = jmin_u + row;
    uint4 v = make_uint4(0u, 0u, 0u, 0u);
    if (j >= 0 && j < SLEN)
      v = *(const uint4*)(qkv + (size_t)(b * SLEN + j) * 768 + 256 + h * 128 + c8 * 8);
    *(uint4*)&KV[row * KPAD + c8 * 8] = v;
  }
  __syncthreads();

  const int koff = w * 16;
  floatx4 sc[8] = {};
#pragma unroll
  for (int kt = 0; kt < 8; ++kt) {
#pragma unroll
    for (int kc = 0; kc < 4; ++kc) {
      short8 kf = *(const short8*)&KV[(koff + kt * 16 + (lane & 15)) * KPAD
                                      + kc * 32 + (lane >> 4) * 8];
      sc[kt] = __builtin_amdgcn_mfma_f32_16x16x32_bf16(qf[kc], kf, sc[kt], 0, 0, 0);
    }
  }

  const int qme = i0 + w * 16 + (lane >> 4) * 4;
  const int jme = jmin_u + koff + (lane & 15);
  float mx[4] = {-1e30f, -1e30f, -1e30f, -1e30f};
#pragma unroll
  for (int kt = 0; kt < 8; ++kt) {
#pragma unroll
    for (int r = 0; r < 4; ++r) {
      int j = jme + kt * 16, q = qme + r;
      bool ok = (j >= 0) && (j >= q - WIN) && (j <= q);
      float s = ok ? sc[kt][r] : -1e30f;
      sc[kt][r] = s;
      mx[r] = fmaxf(mx[r], s);
    }
  }
#pragma unroll
  for (int r = 0; r < 4; ++r)
#pragma unroll
    for (int off = 8; off; off >>= 1) mx[r] = fmaxf(mx[r], __shfl_xor(mx[r], off, 16));

  float sum[4] = {0.f, 0.f, 0.f, 0.f};
#pragma unroll
  for (int kt = 0; kt < 8; ++kt)
#pragma unroll
    for (int r = 0; r < 4; ++r) {
      float e = __expf((sc[kt][r] - mx[r]) * scale);
      sc[kt][r] = e;
      sum[r] += e;
    }
#pragma unroll
  for (int r = 0; r < 4; ++r)
#pragma unroll
    for (int off = 8; off; off >>= 1) sum[r] += __shfl_xor(sum[r], off, 16);
  float rinv[4];
#pragma unroll
  for (int r = 0; r < 4; ++r) rinv[r] = 1.f / sum[r];

  unsigned short* pw = &Ps[w][0];
#pragma unroll
  for (int kt = 0; kt < 8; ++kt)
#pragma unroll
    for (int r = 0; r < 4; ++r)
      pw[((lane >> 4) * 4 + r) * PPAD + kt * 16 + (lane & 15)] = f2bf(sc[kt][r]);
  __syncthreads();

  for (int it = 0; it < 12; ++it) {
    int idx = it * 256 + tid;
    int grp = idx >> 6;
    int key = (grp >> 4) * 64 + (idx & 63);
    int c8  = grp & 15;
    if (key < UNION) {
      int j = jmin_u + key;
      uint4 v = make_uint4(0u, 0u, 0u, 0u);
      if (j >= 0 && j < SLEN)
        v = *(const uint4*)(qkv + (size_t)(b * SLEN + j) * 768 + 512 + h * 128 + c8 * 8);
      unsigned short e[8];
      *(uint4*)e = v;
      int d0 = c8 * 8;
#pragma unroll
      for (int i = 0; i < 8; ++i) KV[(d0 + i) * VPAD + key] = e[i];
    }
  }
  __syncthreads();

  floatx4 ov[8] = {};
#pragma unroll
  for (int kc = 0; kc < 4; ++kc) {
    short8 pf = *(const short8*)&pw[(lane & 15) * PPAD + kc * 32 + (lane >> 4) * 8];
#pragma unroll
    for (int dt = 0; dt < 8; ++dt) {
      short8 vf = *(const short8*)&KV[(dt * 16 + (lane & 15)) * VPAD
                                      + koff + kc * 32 + (lane >> 4) * 8];
      ov[dt] = __builtin_amdgcn_mfma_f32_16x16x32_bf16(pf, vf, ov[dt], 0, 0, 0);
    }
  }

#pragma unroll
  for (int dt = 0; dt < 8; ++dt)
#pragma unroll
    for (int r = 0; r < 4; ++r) {
      int q = qme + r;
      if (q < SLEN)
        ctx[(size_t)(b * SLEN + q) * 256 + h * 128 + dt * 16 + (lane & 15)] =
            f2bf(ov[dt][r] * rinv[r]);
    }
}

// ================= fused post chain — 8 waves/block (2 waves/SIMD) =================
// 250 blocks x 512 thr x 64 tokens. Wave w owns cols [32w,32w+32) in all 3
// stages. B direct from global (L2-resident weights); LDS only for the X1
// transpose + LN cross-wave partials.
__global__ __launch_bounds__(512) void k_post(
    const unsigned short* __restrict__ ctx,
    const unsigned short* __restrict__ wout, const float* __restrict__ bout,
    const unsigned short* __restrict__ xb,
    const float* __restrict__ ln1w, const float* __restrict__ ln1b,
    const unsigned short* __restrict__ w1, const float* __restrict__ b1,
    const unsigned short* __restrict__ w2, const float* __restrict__ b2,
    const float* __restrict__ hp, float* __restrict__ out) {
  __shared__ __align__(16) unsigned short X1[64 * XPAD];     // x1, then h
  __shared__ float lnred[8][64][3];
  __shared__ float lnstat[64][2];
  __shared__ float lnp[512];
  __shared__ float c1s[256];
  const int tid = threadIdx.x, lane = tid & 63, w = tid >> 6;
  const int m0 = blockIdx.x * 64;
  const int kq = lane >> 4, ml = lane & 15;
  const int cb = w * 32;

  if (tid < 256) {
    lnp[tid] = ln1w[tid];
    lnp[256 + tid] = ln1b[tid];
    c1s[tid] = hp[tid];
  }
  const float c0h = hp[256], sc1 = hp[257];

  // ---- stage A: ctx @ Wout^T + bout + x -> LN1 ----
  floatx4 acc[4][2] = {};
#pragma unroll
  for (int k8 = 0; k8 < 8; ++k8) {
    const int kt = k8 * 32;
    short8 af[4];
#pragma unroll
    for (int mt = 0; mt < 4; ++mt)
      af[mt] = *(const short8*)(ctx + (size_t)(m0 + mt * 16 + ml) * 256 + kt + kq * 8);
#pragma unroll
    for (int nt = 0; nt < 2; ++nt) {
      short8 bf = *(const short8*)(wout + (size_t)(cb + nt * 16 + ml) * 256 + kt + kq * 8);
#pragma unroll
      for (int mt = 0; mt < 4; ++mt)
        acc[mt][nt] = __builtin_amdgcn_mfma_f32_16x16x32_bf16(af[mt], bf, acc[mt][nt], 0, 0, 0);
    }
  }
  float s_[4][4], q_[4][4];
#pragma unroll
  for (int mt = 0; mt < 4; ++mt)
#pragma unroll
    for (int r = 0; r < 4; ++r) { s_[mt][r] = 0.f; q_[mt][r] = 0.f; }
#pragma unroll
  for (int mt = 0; mt < 4; ++mt)
#pragma unroll
    for (int nt = 0; nt < 2; ++nt)
#pragma unroll
      for (int r = 0; r < 4; ++r) {
        int lrow = mt * 16 + kq * 4 + r;
        int col  = cb + nt * 16 + ml;
        float v = acc[mt][nt][r] + bout[col]
                + bf2f(xb[(size_t)(m0 + lrow) * 256 + col]);
        acc[mt][nt][r] = v;
        s_[mt][r] += v;
        q_[mt][r] += v * v;
      }
#pragma unroll
  for (int mt = 0; mt < 4; ++mt)
#pragma unroll
    for (int r = 0; r < 4; ++r) {
#pragma unroll
      for (int off = 8; off; off >>= 1) {
        s_[mt][r] += __shfl_xor(s_[mt][r], off, 16);
        q_[mt][r] += __shfl_xor(q_[mt][r], off, 16);
      }
      if (ml == 0) {
        int lrow = mt * 16 + kq * 4 + r;
        lnred[w][lrow][0] = s_[mt][r];
        lnred[w][lrow][1] = q_[mt][r];
      }
    }
  __syncthreads();
  if (tid < 64) {
    float s = 0.f, q = 0.f;
#pragma unroll
    for (int i = 0; i < 8; ++i) { s += lnred[i][tid][0]; q += lnred[i][tid][1]; }
    float mu  = s * (1.f / 256.f);
    float var = q * (1.f / 256.f) - mu * mu;
    lnstat[tid][0] = mu;
    lnstat[tid][1] = rsqrtf(var + 1e-5f);
  }
  __syncthreads();
  floatx4 x1sav[4][2];
#pragma unroll
  for (int mt = 0; mt < 4; ++mt)
#pragma unroll
    for (int r = 0; r < 4; ++r) {
      int lrow = mt * 16 + kq * 4 + r;
      float mu = lnstat[lrow][0], rr = lnstat[lrow][1];
#pragma unroll
      for (int nt = 0; nt < 2; ++nt) {
        int col = cb + nt * 16 + ml;
        float x1 = (acc[mt][nt][r] - mu) * rr * lnp[col] + lnp[256 + col];
        x1sav[mt][nt][r] = x1;
        X1[lrow * XPAD + col] = f2bf(x1);
      }
    }
  __syncthreads();

  // ---- stage B: h = relu(x1 @ W1^T + b1) ----
#pragma unroll
  for (int mt = 0; mt < 4; ++mt)
#pragma unroll
    for (int nt = 0; nt < 2; ++nt) acc[mt][nt] = (floatx4){0.f, 0.f, 0.f, 0.f};
#pragma unroll
  for (int k8 = 0; k8 < 8; ++k8) {
    const int kt = k8 * 32;
    short8 af[4];
#pragma unroll
    for (int mt = 0; mt < 4; ++mt)
      af[mt] = *(const short8*)&X1[(mt * 16 + ml) * XPAD + kt + kq * 8];
#pragma unroll
    for (int nt = 0; nt < 2; ++nt) {
      short8 bf = *(const short8*)(w1 + (size_t)(cb + nt * 16 + ml) * 256 + kt + kq * 8);
#pragma unroll
      for (int mt = 0; mt < 4; ++mt)
        acc[mt][nt] = __builtin_amdgcn_mfma_f32_16x16x32_bf16(af[mt], bf, acc[mt][nt], 0, 0, 0);
    }
  }
  __syncthreads();   // all waves done reading x1 before h overwrite
#pragma unroll
  for (int mt = 0; mt < 4; ++mt)
#pragma unroll
    for (int nt = 0; nt < 2; ++nt)
#pragma unroll
      for (int r = 0; r < 4; ++r) {
        int lrow = mt * 16 + kq * 4 + r;
        int col  = cb + nt * 16 + ml;
        X1[lrow * XPAD + col] = f2bf(fmaxf(acc[mt][nt][r] + b1[col], 0.f));
      }
  __syncthreads();

  // ---- stage C: o = h @ W2^T + b2 + x1 -> LN2 + collapsed head ----
#pragma unroll
  for (int mt = 0; mt < 4; ++mt)
#pragma unroll
    for (int nt = 0; nt < 2; ++nt) acc[mt][nt] = (floatx4){0.f, 0.f, 0.f, 0.f};
#pragma unroll
  for (int k8 = 0; k8 < 8; ++k8) {
    const int kt = k8 * 32;
    short8 af[4];
#pragma unroll
    for (int mt = 0; mt < 4; ++mt)
      af[mt] = *(const short8*)&X1[(mt * 16 + ml) * XPAD + kt + kq * 8];
#pragma unroll
    for (int nt = 0; nt < 2; ++nt) {
      short8 bf = *(const short8*)(w2 + (size_t)(cb + nt * 16 + ml) * 256 + kt + kq * 8);
#pragma unroll
      for (int mt = 0; mt < 4; ++mt)
        acc[mt][nt] = __builtin_amdgcn_mfma_f32_16x16x32_bf16(af[mt], bf, acc[mt][nt], 0, 0, 0);
    }
  }
  float ss[4][4], qq[4][4], dd[4][4];
#pragma unroll
  for (int mt = 0; mt < 4; ++mt)
#pragma unroll
    for (int r = 0; r < 4; ++r) { ss[mt][r] = 0.f; qq[mt][r] = 0.f; dd[mt][r] = 0.f; }
#pragma unroll
  for (int mt = 0; mt < 4; ++mt)
#pragma unroll
    for (int nt = 0; nt < 2; ++nt)
#pragma unroll
      for (int r = 0; r < 4; ++r) {
        int col = cb + nt * 16 + ml;
        float v = acc[mt][nt][r] + b2[col] + x1sav[mt][nt][r];
        ss[mt][r] += v;
        qq[mt][r] += v * v;
        dd[mt][r] += v * c1s[col];
      }
#pragma unroll
  for (int mt = 0; mt < 4; ++mt)
#pragma unroll
    for (int r = 0; r < 4; ++r) {
#pragma unroll
      for (int off = 8; off; off >>= 1) {
        ss[mt][r] += __shfl_xor(ss[mt][r], off, 16);
        qq[mt][r] += __shfl_xor(qq[mt][r], off, 16);
        dd[mt][r] += __shfl_xor(dd[mt][r], off, 16);
      }
      if (ml == 0) {
        int lrow = mt * 16 + kq * 4 + r;
        lnred[w][lrow][0] = ss[mt][r];
        lnred[w][lrow][1] = qq[mt][r];
        lnred[w][lrow][2] = dd[mt][r];
      }
    }
  __syncthreads();
  if (tid < 64) {
    float s = 0.f, q = 0.f, d = 0.f;
#pragma unroll
    for (int i = 0; i < 8; ++i) {
      s += lnred[i][tid][0];
      q += lnred[i][tid][1];
      d += lnred[i][tid][2];
    }
    float mu  = s * (1.f / 256.f);
    float var = q * (1.f / 256.f) - mu * mu;
    float rr  = rsqrtf(var + 1e-5f);
    out[m0 + tid] = rr * (d - mu * sc1) + c0h;
  }
}

extern "C" void kernel_launch(void* const* d_in, const int* in_sizes, int n_in,
                              void* d_out, int out_size, void* d_ws, size_t ws_size,
                              hipStream_t stream) {
  const float* src        = (const float*)d_in[0];
  // d_in[1] = input_lengths (unused)
  const float* W_enc      = (const float*)d_in[2];
  const float* b_enc      = (const float*)d_in[3];
  const float* in_proj_w  = (const float*)d_in[4];
  const float* in_proj_b  = (const float*)d_in[5];
  const float* out_proj_w = (const float*)d_in[6];
  const float* out_proj_b = (const float*)d_in[7];
  const float* ln1_w      = (const float*)d_in[8];
  const float* ln1_b      = (const float*)d_in[9];
  const float* lin1_w     = (const float*)d_in[10];
  const float* lin1_b     = (const float*)d_in[11];
  const float* lin2_w     = (const float*)d_in[12];
  const float* lin2_b     = (const float*)d_in[13];
  const float* ln2_w      = (const float*)d_in[14];
  const float* ln2_b      = (const float*)d_in[15];
  const float* fc1_w      = (const float*)d_in[16];
  const float* fc1_b      = (const float*)d_in[17];
  const float* fc2_w      = (const float*)d_in[18];
  const float* fc2_b      = (const float*)d_in[19];

  char* p = (char*)d_ws;
  float* pe            = (float*)p;           p += (size_t)SLEN * 256 * 4;
  float* hp            = (float*)p;           p += 2048;   // 258 floats used
  unsigned short* xb   = (unsigned short*)p;  p += (size_t)MTOK * 256 * 2;
  unsigned short* qkvb = (unsigned short*)p;  p += (size_t)MTOK * 768 * 2;
  unsigned short* ctxb = (unsigned short*)p;  p += (size_t)MTOK * 256 * 2;
  unsigned short* wencb= (unsigned short*)p;  p += 256 * 256 * 2;
  unsigned short* wqkb = (unsigned short*)p;  p += 768 * 256 * 2;
  unsigned short* woutb= (unsigned short*)p;  p += 256 * 256 * 2;
  unsigned short* wl1b = (unsigned short*)p;  p += 256 * 256 * 2;
  unsigned short* wl2b = (unsigned short*)p;  p += 256 * 256 * 2;

  k_prep<<<949, 256, 0, stream>>>(W_enc, wencb, in_proj_w, wqkb,
                                  out_proj_w, woutb, lin1_w, wl1b, lin2_w, wl2b,
                                  pe, fc1_w, fc1_b, fc2_w, fc2_b, ln2_w, ln2_b, hp);
  k_pre<<<MTOK / 64, 512, 0, stream>>>(src, wencb, b_enc, pe, wqkb, in_proj_b, xb, qkvb);
  k_attn_mfma<<<dim3((SLEN + 63) / 64, BATCH, 2), 256, 0, stream>>>(qkvb, ctxb);
  k_post<<<MTOK / 64, 512, 0, stream>>>(ctxb, woutb, out_proj_b, xb, ln1_w, ln1_b,
                                        wl1b, lin1_b, wl2b, lin2_b, hp, (float*)d_out);
}